// Round 21
// baseline (48.799 us; speedup 1.0000x reference)
//
#include <hip/hip_runtime.h>

// DynamicWeights, fused MFMA kernel. R21 = R17 + R20's conflict-free combine
// addressing (reuse the MFMA B-read pattern: lane L owns pixels L and L+16 of
// row q, 16 channels) but with SPILL-PROOF math: plain f32 accumulators,
// static indices, tiny unrolled bodies (R20's packed-f16 aggregates spilled).
// Residual folded into filter tap 4 (+1.0 at softmax write).
//  K0 k_wprep: weights -> MFMA A-fragment blob (f16), rows 9..15 zeroed.
//  K1 k_main: 32x4 px tile, 4 waves, 30KB LDS (5 blocks/CU); one barrier;
//     conv mfma_f32_16x16x32_f16; shfl softmax; wave-local fb; f32 combine.
// x: (8,64,192,192) f32, conv_w: (9,64,3,3) f32, gamma: (1,) f32

constexpr int Nn = 8, Cc = 64, Hh = 192, Ww = 192;
constexpr int HW  = Hh * Ww;
constexpr int NKB = 18;                 // K-blocks: 576/32
constexpr int BLOB_N = NKB * 64 * 8;    // 9216 f16
constexpr int TX = 32, TY = 4;          // pixel tile (128 px)
constexpr int SR = TY + 2, SC = TX + 2; // staged rows/cols: 6 x 34
constexpr int NSTG = SR * SC * 8;       // 1632 staging units (8ch each)
constexpr int FBS = 16;                 // fbuf stride (shorts) per pixel
constexpr int GX = Ww / TX, GY = Hh / TY;          // 6, 48
constexpr int NWG = GX * GY * Nn;                  // 2304 (% 8 == 0)
constexpr int CPX = NWG / 8;                       // 288 tiles per XCD chunk

typedef _Float16 f16x8 __attribute__((ext_vector_type(8)));
typedef float    f32x4 __attribute__((ext_vector_type(4)));
typedef __fp16   fp16x2 __attribute__((ext_vector_type(2)));

__device__ __forceinline__ unsigned pkh(float a, float b) {
    fp16x2 h = __builtin_amdgcn_cvt_pkrtz(a, b);
    union { fp16x2 h; unsigned u; } v; v.h = h;
    return v.u;
}
__device__ __forceinline__ unsigned short f2h(float f) {
    union { _Float16 h; unsigned short s; } v; v.h = (_Float16)f;
    return v.s;
}
__device__ __forceinline__ float h2f(unsigned short s) {
    union { unsigned short s; _Float16 h; } v; v.s = s;
    return (float)v.h;
}

// ---- K0: weight blob in A-fragment layout (validated R7-R20) ----
__global__ __launch_bounds__(256)
void k_wprep(const float* __restrict__ cw, unsigned short* __restrict__ blob) {
    int idx = blockIdx.x * 256 + threadIdx.x;
    if (idx < BLOB_N) {
        int j  = idx & 7;
        int l  = (idx >> 3) & 63;
        int kb = idx >> 9;
        int k  = kb * 32 + ((l >> 4) << 3) + j;
        int m  = l & 15;
        int p  = k >> 6, c = k & 63;
        float v = (m < 9) ? cw[(m * Cc + c) * 9 + p] : 0.f;
        blob[idx] = f2h(v);
    }
}

// ---- K1: fused conv + softmax + combine, 4 waves, ONE barrier ----
__global__ __launch_bounds__(256, 5)
void k_main(const float* __restrict__ x, const unsigned short* __restrict__ blob,
            const float* __restrict__ gamma, float* __restrict__ out)
{
    __shared__ short xs[SR * SC * 64];   // 26112 B, swizzled [row][col][ch], f16
    __shared__ short fb[128 * FBS];      // 4096 B: per-pixel 9 filter taps (f16)

    // XCD-aware bijective swizzle (2304 % 8 == 0)
    const int b  = blockIdx.x;
    const int wt = (b & 7) * CPX + (b >> 3);
    const int bx = wt % GX;
    const int r2 = wt / GX;
    const int by = r2 % GY;
    const int n  = r2 / GY;

    const int tid  = threadIdx.x;
    const int lane = tid & 63, q = tid >> 6;       // wave q: pixel row q (0..3)
    const int w0 = bx * TX, h0 = by * TY;
    const float* __restrict__ xn = x + (size_t)n * Cc * HW;

    f16x8 af[NKB];
#pragma unroll
    for (int kb = 0; kb < NKB; ++kb)
        af[kb] = *(const f16x8*)(blob + (kb * 64 + lane) * 8);

    // ---- stage tile (R17-validated) ----
#pragma unroll
    for (int i = 0; i < 7; ++i) {
        int idx = tid + i * 256;
        if (idx < NSTG) {
            int col  = idx % SC;
            int rest = idx / SC;
            int row  = rest % SR, cg = rest / SR;
            int gh = h0 + row - 1, gw = w0 + col - 1;
            bool ok = ((unsigned)gh < (unsigned)Hh) && ((unsigned)gw < (unsigned)Ww);
            const float* src = xn + (size_t)(cg * 8) * HW + gh * Ww + gw;
            float v[8];
#pragma unroll
            for (int j = 0; j < 8; ++j)
                v[j] = ok ? src[(size_t)j * HW] : 0.f;
            int widx = (row * SC + col) * 64 + ((cg ^ (col & 7)) << 3);
            *(int4*)&xs[widx] = make_int4(pkh(v[0], v[1]), pkh(v[2], v[3]),
                                          pkh(v[4], v[5]), pkh(v[6], v[7]));
        }
    }
    __syncthreads();   // the ONLY barrier

    // ---- MFMA conv (unchanged) ----
    const int g8 = (lane >> 4) << 3;
    int cbase[3], chg[3][2];
#pragma unroll
    for (int dj = 0; dj < 3; ++dj) {
        int swz = (((lane & 15) + dj) & 7) << 3;
        chg[dj][0] = g8 ^ swz;
        chg[dj][1] = (32 | g8) ^ swz;
        cbase[dj]  = (q * SC + (lane & 15) + dj) * 64;
    }

    f32x4 z = {0.f, 0.f, 0.f, 0.f};
    f32x4 acc0 = z, acc1 = z;

#pragma unroll
    for (int kb = 0; kb < NKB; ++kb) {
        const int p = kb >> 1, di = p / 3, dj = p % 3, ch = kb & 1;
        const int a0 = cbase[dj] + di * (SC * 64) + chg[dj][ch];
        f16x8 b0 = *(const f16x8*)&xs[a0];
        f16x8 b1 = *(const f16x8*)&xs[a0 + 16 * 64];
        acc0 = __builtin_amdgcn_mfma_f32_16x16x32_f16(af[kb], b0, acc0, 0, 0, 0);
        acc1 = __builtin_amdgcn_mfma_f32_16x16x32_f16(af[kb], b1, acc1, 0, 0, 0);
    }

    // ---- softmax (shfl), filter -> fb; +1.0 folded into tap 4 ----
    const float g0 = gamma[0];
    const int gidx = lane >> 4;
    const int k0 = gidx * 4;
    const float NEG = -3.0e38f;
    const float b4 = (gidx == 1) ? 1.f : 0.f;   // k0==4 -> e0 slot is tap 4

    f32x4 accs[2] = {acc0, acc1};
#pragma unroll
    for (int mt = 0; mt < 2; ++mt) {
        float a0 = accs[mt][0], a1 = accs[mt][1], a2 = accs[mt][2], a3 = accs[mt][3];
        float m0 = (gidx < 3) ? a0 : NEG;
        float m1 = (gidx < 2) ? a1 : NEG;
        float m2 = (gidx < 2) ? a2 : NEG;
        float m3 = (gidx < 2) ? a3 : NEG;
        float m = fmaxf(fmaxf(m0, m1), fmaxf(m2, m3));
        m = fmaxf(m, __shfl_xor(m, 16));
        m = fmaxf(m, __shfl_xor(m, 32));
        float e0 = (gidx < 3) ? __expf(a0 - m) : 0.f;
        float e1 = (gidx < 2) ? __expf(a1 - m) : 0.f;
        float e2 = (gidx < 2) ? __expf(a2 - m) : 0.f;
        float e3 = (gidx < 2) ? __expf(a3 - m) : 0.f;
        float s = (e0 + e1) + (e2 + e3);
        s += __shfl_xor(s, 16);
        s += __shfl_xor(s, 32);
        const float gs = g0 / s;
        const int px = q * 32 + mt * 16 + (lane & 15);
        if (gidx < 2) {
            *(unsigned*)&fb[px * FBS + k0]     = pkh(e0 * gs + b4, e1 * gs);
            *(unsigned*)&fb[px * FBS + k0 + 2] = pkh(e2 * gs, e3 * gs);
        } else if (gidx == 2) {
            fb[px * FBS + 8] = f2h(e0 * gs);
        }
    }
    // NO barrier: wave q reads back only row-q filters (lgkmcnt orders DS ops)

    // ---- pass 2: combine, MFMA-pattern addressing, plain f32 accumulators ----
    // lane owns pixels pxA = (lane&15) and pxB = pxA+16 of row q; 16 channels
    // {g8..g8+7, 32+g8..32+g8+7}. Taps of pixel L are staged cols L+dj.
    float fA[9], fB[9];
    {
        const int pxA = q * 32 + (lane & 15);
        union { int4 i; f16x8 h; } ca; ca.i = *(const int4*)&fb[pxA * FBS];
        union { int4 i; f16x8 h; } cb; cb.i = *(const int4*)&fb[(pxA + 16) * FBS];
#pragma unroll
        for (int k = 0; k < 8; ++k) { fA[k] = (float)ca.h[k]; fB[k] = (float)cb.h[k]; }
        fA[8] = h2f((unsigned short)fb[pxA * FBS + 8]);
        fB[8] = h2f((unsigned short)fb[(pxA + 16) * FBS + 8]);
    }

    float aA0[8], aA1[8], aB0[8], aB1[8];   // [ch-half][8 ch], static idx only
#pragma unroll
    for (int j = 0; j < 8; ++j) { aA0[j] = 0.f; aA1[j] = 0.f; aB0[j] = 0.f; aB1[j] = 0.f; }

#pragma unroll
    for (int p = 0; p < 9; ++p) {
        const int di = p / 3, dj = p % 3;
        const int base = cbase[dj] + di * (SC * 64);
        // ch-half 0 (channels g8^swz group of half 0)
        {
            union { int4 i; f16x8 h; } c0; c0.i = *(const int4*)&xs[base + chg[dj][0]];
            union { int4 i; f16x8 h; } c1; c1.i = *(const int4*)&xs[base + chg[dj][0] + 16 * 64];
#pragma unroll
            for (int j = 0; j < 8; ++j) {
                aA0[j] = fmaf(fA[p], (float)c0.h[j], aA0[j]);
                aB0[j] = fmaf(fB[p], (float)c1.h[j], aB0[j]);
            }
        }
        // ch-half 1
        {
            union { int4 i; f16x8 h; } c0; c0.i = *(const int4*)&xs[base + chg[dj][1]];
            union { int4 i; f16x8 h; } c1; c1.i = *(const int4*)&xs[base + chg[dj][1] + 16 * 64];
#pragma unroll
            for (int j = 0; j < 8; ++j) {
                aA1[j] = fmaf(fA[p], (float)c0.h[j], aA1[j]);
                aB1[j] = fmaf(fB[p], (float)c1.h[j], aB1[j]);
            }
        }
    }

    // ---- store: 2 px x 16 ch, scalar dwords ----
    float* outp = out + (size_t)n * Cc * HW + (size_t)(h0 + q) * Ww + (w0 + (lane & 15));
#pragma unroll
    for (int j = 0; j < 8; ++j) {
        outp[(size_t)(g8 + j) * HW]            = aA0[j];
        outp[(size_t)(32 + g8 + j) * HW]       = aA1[j];
        outp[(size_t)(g8 + j) * HW + 16]       = aB0[j];
        outp[(size_t)(32 + g8 + j) * HW + 16]  = aB1[j];
    }
}

extern "C" void kernel_launch(void* const* d_in, const int* in_sizes, int n_in,
                              void* d_out, int out_size, void* d_ws, size_t ws_size,
                              hipStream_t stream) {
    const float* x  = (const float*)d_in[0];
    const float* cw = (const float*)d_in[1];
    const float* gm = (const float*)d_in[2];
    float* out = (float*)d_out;
    unsigned short* blob = (unsigned short*)d_ws;   // 9216 f16 = 18 KB

    k_wprep<<<dim3((BLOB_N + 255) / 256), dim3(256), 0, stream>>>(cw, blob);
    k_main <<<dim3(NWG), dim3(256), 0, stream>>>(x, blob, gm, out);
}

// Round 22
// 45.139 us; speedup vs baseline: 1.0811x; 1.0811x over previous
//
#include <hip/hip_runtime.h>

// DynamicWeights, fused MFMA kernel. R22 = R17 structure + R20's conflict-free
// combine addressing, restructured to R17's LIVENESS PROFILE: per channel-half
// compute 16 f32 accs and store immediately (R20/R21 held 32+ accs live across
// the tap loop -> spill; R17's store-per-subset never spilled).
// Residual folded into filter tap 4 (+1.0 at softmax write; validated R20/21).
//  K0 k_wprep: weights -> MFMA A-fragment blob (f16), rows 9..15 zeroed.
//  K1 k_main: 32x4 px tile, 4 waves, 30KB LDS (5 blocks/CU); one barrier;
//     conv mfma_f32_16x16x32_f16; shfl softmax; wave-local fb; f32 combine.
// x: (8,64,192,192) f32, conv_w: (9,64,3,3) f32, gamma: (1,) f32

constexpr int Nn = 8, Cc = 64, Hh = 192, Ww = 192;
constexpr int HW  = Hh * Ww;
constexpr int NKB = 18;                 // K-blocks: 576/32
constexpr int BLOB_N = NKB * 64 * 8;    // 9216 f16
constexpr int TX = 32, TY = 4;          // pixel tile (128 px)
constexpr int SR = TY + 2, SC = TX + 2; // staged rows/cols: 6 x 34
constexpr int NSTG = SR * SC * 8;       // 1632 staging units (8ch each)
constexpr int FBS = 16;                 // fbuf stride (shorts) per pixel
constexpr int GX = Ww / TX, GY = Hh / TY;          // 6, 48
constexpr int NWG = GX * GY * Nn;                  // 2304 (% 8 == 0)
constexpr int CPX = NWG / 8;                       // 288 tiles per XCD chunk

typedef _Float16 f16x8 __attribute__((ext_vector_type(8)));
typedef float    f32x4 __attribute__((ext_vector_type(4)));
typedef __fp16   fp16x2 __attribute__((ext_vector_type(2)));

__device__ __forceinline__ unsigned pkh(float a, float b) {
    fp16x2 h = __builtin_amdgcn_cvt_pkrtz(a, b);
    union { fp16x2 h; unsigned u; } v; v.h = h;
    return v.u;
}
__device__ __forceinline__ unsigned short f2h(float f) {
    union { _Float16 h; unsigned short s; } v; v.h = (_Float16)f;
    return v.s;
}
__device__ __forceinline__ float h2f(unsigned short s) {
    union { unsigned short s; _Float16 h; } v; v.s = s;
    return (float)v.h;
}

// ---- K0: weight blob in A-fragment layout (validated R7-R21) ----
__global__ __launch_bounds__(256)
void k_wprep(const float* __restrict__ cw, unsigned short* __restrict__ blob) {
    int idx = blockIdx.x * 256 + threadIdx.x;
    if (idx < BLOB_N) {
        int j  = idx & 7;
        int l  = (idx >> 3) & 63;
        int kb = idx >> 9;
        int k  = kb * 32 + ((l >> 4) << 3) + j;
        int m  = l & 15;
        int p  = k >> 6, c = k & 63;
        float v = (m < 9) ? cw[(m * Cc + c) * 9 + p] : 0.f;
        blob[idx] = f2h(v);
    }
}

// ---- K1: fused conv + softmax + combine, 4 waves, ONE barrier ----
__global__ __launch_bounds__(256, 5)
void k_main(const float* __restrict__ x, const unsigned short* __restrict__ blob,
            const float* __restrict__ gamma, float* __restrict__ out)
{
    __shared__ short xs[SR * SC * 64];   // 26112 B, swizzled [row][col][ch], f16
    __shared__ short fb[128 * FBS];      // 4096 B: per-pixel 9 filter taps (f16)

    // XCD-aware bijective swizzle (2304 % 8 == 0)
    const int b  = blockIdx.x;
    const int wt = (b & 7) * CPX + (b >> 3);
    const int bx = wt % GX;
    const int r2 = wt / GX;
    const int by = r2 % GY;
    const int n  = r2 / GY;

    const int tid  = threadIdx.x;
    const int lane = tid & 63, q = tid >> 6;       // wave q: pixel row q (0..3)
    const int w0 = bx * TX, h0 = by * TY;
    const float* __restrict__ xn = x + (size_t)n * Cc * HW;

    f16x8 af[NKB];
#pragma unroll
    for (int kb = 0; kb < NKB; ++kb)
        af[kb] = *(const f16x8*)(blob + (kb * 64 + lane) * 8);

    // ---- stage tile (R17-validated) ----
#pragma unroll
    for (int i = 0; i < 7; ++i) {
        int idx = tid + i * 256;
        if (idx < NSTG) {
            int col  = idx % SC;
            int rest = idx / SC;
            int row  = rest % SR, cg = rest / SR;
            int gh = h0 + row - 1, gw = w0 + col - 1;
            bool ok = ((unsigned)gh < (unsigned)Hh) && ((unsigned)gw < (unsigned)Ww);
            const float* src = xn + (size_t)(cg * 8) * HW + gh * Ww + gw;
            float v[8];
#pragma unroll
            for (int j = 0; j < 8; ++j)
                v[j] = ok ? src[(size_t)j * HW] : 0.f;
            int widx = (row * SC + col) * 64 + ((cg ^ (col & 7)) << 3);
            *(int4*)&xs[widx] = make_int4(pkh(v[0], v[1]), pkh(v[2], v[3]),
                                          pkh(v[4], v[5]), pkh(v[6], v[7]));
        }
    }
    __syncthreads();   // the ONLY barrier

    // ---- MFMA conv (unchanged) ----
    const int g8 = (lane >> 4) << 3;
    int cbase[3], chg[3][2];
#pragma unroll
    for (int dj = 0; dj < 3; ++dj) {
        int swz = (((lane & 15) + dj) & 7) << 3;
        chg[dj][0] = g8 ^ swz;
        chg[dj][1] = (32 | g8) ^ swz;
        cbase[dj]  = (q * SC + (lane & 15) + dj) * 64;
    }

    f32x4 z = {0.f, 0.f, 0.f, 0.f};
    f32x4 acc0 = z, acc1 = z;

#pragma unroll
    for (int kb = 0; kb < NKB; ++kb) {
        const int p = kb >> 1, di = p / 3, dj = p % 3, ch = kb & 1;
        const int a0 = cbase[dj] + di * (SC * 64) + chg[dj][ch];
        f16x8 b0 = *(const f16x8*)&xs[a0];
        f16x8 b1 = *(const f16x8*)&xs[a0 + 16 * 64];
        acc0 = __builtin_amdgcn_mfma_f32_16x16x32_f16(af[kb], b0, acc0, 0, 0, 0);
        acc1 = __builtin_amdgcn_mfma_f32_16x16x32_f16(af[kb], b1, acc1, 0, 0, 0);
    }

    // ---- softmax (shfl), filter -> fb; +1.0 folded into tap 4 ----
    const float g0 = gamma[0];
    const int gidx = lane >> 4;
    const int k0 = gidx * 4;
    const float NEG = -3.0e38f;
    const float b4 = (gidx == 1) ? 1.f : 0.f;   // k0==4 -> e0 slot is tap 4

    f32x4 accs[2] = {acc0, acc1};
#pragma unroll
    for (int mt = 0; mt < 2; ++mt) {
        float a0 = accs[mt][0], a1 = accs[mt][1], a2 = accs[mt][2], a3 = accs[mt][3];
        float m0 = (gidx < 3) ? a0 : NEG;
        float m1 = (gidx < 2) ? a1 : NEG;
        float m2 = (gidx < 2) ? a2 : NEG;
        float m3 = (gidx < 2) ? a3 : NEG;
        float m = fmaxf(fmaxf(m0, m1), fmaxf(m2, m3));
        m = fmaxf(m, __shfl_xor(m, 16));
        m = fmaxf(m, __shfl_xor(m, 32));
        float e0 = (gidx < 3) ? __expf(a0 - m) : 0.f;
        float e1 = (gidx < 2) ? __expf(a1 - m) : 0.f;
        float e2 = (gidx < 2) ? __expf(a2 - m) : 0.f;
        float e3 = (gidx < 2) ? __expf(a3 - m) : 0.f;
        float s = (e0 + e1) + (e2 + e3);
        s += __shfl_xor(s, 16);
        s += __shfl_xor(s, 32);
        const float gs = g0 / s;
        const int px = q * 32 + mt * 16 + (lane & 15);
        if (gidx < 2) {
            *(unsigned*)&fb[px * FBS + k0]     = pkh(e0 * gs + b4, e1 * gs);
            *(unsigned*)&fb[px * FBS + k0 + 2] = pkh(e2 * gs, e3 * gs);
        } else if (gidx == 2) {
            fb[px * FBS + 8] = f2h(e0 * gs);
        }
    }
    // NO barrier: wave q reads back only row-q filters (lgkmcnt orders DS ops)

    // ---- pass 2: combine, conflict-free addressing, R17 liveness profile ----
    // lane owns pixels pxA = (lane&15) and pxB = pxA+16 of row q.
    // Per ch-half: 16 accs, 18 LDS reads, store immediately.
    float fA[9], fB[9];
    {
        const int pxA = q * 32 + (lane & 15);
        union { int4 i; f16x8 h; } ca; ca.i = *(const int4*)&fb[pxA * FBS];
        union { int4 i; f16x8 h; } cb; cb.i = *(const int4*)&fb[(pxA + 16) * FBS];
#pragma unroll
        for (int k = 0; k < 8; ++k) { fA[k] = (float)ca.h[k]; fB[k] = (float)cb.h[k]; }
        fA[8] = h2f((unsigned short)fb[pxA * FBS + 8]);
        fB[8] = h2f((unsigned short)fb[(pxA + 16) * FBS + 8]);
    }

    float* outp = out + (size_t)n * Cc * HW + (size_t)(h0 + q) * Ww + (w0 + (lane & 15));

#pragma unroll
    for (int hh = 0; hh < 2; ++hh) {
        float aA[8], aB[8];
#pragma unroll
        for (int j = 0; j < 8; ++j) { aA[j] = 0.f; aB[j] = 0.f; }
#pragma unroll
        for (int p = 0; p < 9; ++p) {
            const int di = p / 3, dj = p % 3;
            const int base = cbase[dj] + di * (SC * 64) + chg[dj][hh];
            union { int4 i; f16x8 h; } c0; c0.i = *(const int4*)&xs[base];
            union { int4 i; f16x8 h; } c1; c1.i = *(const int4*)&xs[base + 16 * 64];
#pragma unroll
            for (int j = 0; j < 8; ++j) {
                aA[j] = fmaf(fA[p], (float)c0.h[j], aA[j]);
                aB[j] = fmaf(fB[p], (float)c1.h[j], aB[j]);
            }
        }
        const int c0 = hh * 32 + g8;
#pragma unroll
        for (int j = 0; j < 8; ++j) {
            outp[(size_t)(c0 + j) * HW]      = aA[j];
            outp[(size_t)(c0 + j) * HW + 16] = aB[j];
        }
    }
}

extern "C" void kernel_launch(void* const* d_in, const int* in_sizes, int n_in,
                              void* d_out, int out_size, void* d_ws, size_t ws_size,
                              hipStream_t stream) {
    const float* x  = (const float*)d_in[0];
    const float* cw = (const float*)d_in[1];
    const float* gm = (const float*)d_in[2];
    float* out = (float*)d_out;
    unsigned short* blob = (unsigned short*)d_ws;   // 9216 f16 = 18 KB

    k_wprep<<<dim3((BLOB_N + 255) / 256), dim3(256), 0, stream>>>(cw, blob);
    k_main <<<dim3(NWG), dim3(256), 0, stream>>>(x, blob, gm, out);
}

// Round 23
// 40.539 us; speedup vs baseline: 1.2038x; 1.1135x over previous
//
#include <hip/hip_runtime.h>

// DynamicWeights, fused MFMA kernel. R23 = R22 with ZERO cross-phase array
// liveness: cbase/chg scoped to the MFMA block (die before softmax); the
// conflict-free combine recomputes all LDS addresses inline from lane/q/p/hh
// (R17's spill-proof shape + R20's conflict-free pattern + tap-4 residual fold).
//  K0 k_wprep: weights -> MFMA A-fragment blob (f16), rows 9..15 zeroed.
//  K1 k_main: 32x4 px tile, 4 waves, 30KB LDS (5 blocks/CU); one barrier;
//     conv mfma_f32_16x16x32_f16; shfl softmax; wave-local fb; f32 combine.
// x: (8,64,192,192) f32, conv_w: (9,64,3,3) f32, gamma: (1,) f32

constexpr int Nn = 8, Cc = 64, Hh = 192, Ww = 192;
constexpr int HW  = Hh * Ww;
constexpr int NKB = 18;                 // K-blocks: 576/32
constexpr int BLOB_N = NKB * 64 * 8;    // 9216 f16
constexpr int TX = 32, TY = 4;          // pixel tile (128 px)
constexpr int SR = TY + 2, SC = TX + 2; // staged rows/cols: 6 x 34
constexpr int NSTG = SR * SC * 8;       // 1632 staging units (8ch each)
constexpr int FBS = 16;                 // fbuf stride (shorts) per pixel
constexpr int GX = Ww / TX, GY = Hh / TY;          // 6, 48
constexpr int NWG = GX * GY * Nn;                  // 2304 (% 8 == 0)
constexpr int CPX = NWG / 8;                       // 288 tiles per XCD chunk

typedef _Float16 f16x8 __attribute__((ext_vector_type(8)));
typedef float    f32x4 __attribute__((ext_vector_type(4)));
typedef __fp16   fp16x2 __attribute__((ext_vector_type(2)));

__device__ __forceinline__ unsigned pkh(float a, float b) {
    fp16x2 h = __builtin_amdgcn_cvt_pkrtz(a, b);
    union { fp16x2 h; unsigned u; } v; v.h = h;
    return v.u;
}
__device__ __forceinline__ unsigned short f2h(float f) {
    union { _Float16 h; unsigned short s; } v; v.h = (_Float16)f;
    return v.s;
}
__device__ __forceinline__ float h2f(unsigned short s) {
    union { unsigned short s; _Float16 h; } v; v.s = s;
    return (float)v.h;
}

// ---- K0: weight blob in A-fragment layout (validated R7-R22) ----
__global__ __launch_bounds__(256)
void k_wprep(const float* __restrict__ cw, unsigned short* __restrict__ blob) {
    int idx = blockIdx.x * 256 + threadIdx.x;
    if (idx < BLOB_N) {
        int j  = idx & 7;
        int l  = (idx >> 3) & 63;
        int kb = idx >> 9;
        int k  = kb * 32 + ((l >> 4) << 3) + j;
        int m  = l & 15;
        int p  = k >> 6, c = k & 63;
        float v = (m < 9) ? cw[(m * Cc + c) * 9 + p] : 0.f;
        blob[idx] = f2h(v);
    }
}

// ---- K1: fused conv + softmax + combine, 4 waves, ONE barrier ----
__global__ __launch_bounds__(256, 5)
void k_main(const float* __restrict__ x, const unsigned short* __restrict__ blob,
            const float* __restrict__ gamma, float* __restrict__ out)
{
    __shared__ short xs[SR * SC * 64];   // 26112 B, swizzled [row][col][ch], f16
    __shared__ short fb[128 * FBS];      // 4096 B: per-pixel 9 filter taps (f16)

    // XCD-aware bijective swizzle (2304 % 8 == 0)
    const int b  = blockIdx.x;
    const int wt = (b & 7) * CPX + (b >> 3);
    const int bx = wt % GX;
    const int r2 = wt / GX;
    const int by = r2 % GY;
    const int n  = r2 / GY;

    const int tid  = threadIdx.x;
    const int lane = tid & 63, q = tid >> 6;       // wave q: pixel row q (0..3)
    const int w0 = bx * TX, h0 = by * TY;
    const float* __restrict__ xn = x + (size_t)n * Cc * HW;

    f16x8 af[NKB];
#pragma unroll
    for (int kb = 0; kb < NKB; ++kb)
        af[kb] = *(const f16x8*)(blob + (kb * 64 + lane) * 8);

    // ---- stage tile (R17-validated) ----
#pragma unroll
    for (int i = 0; i < 7; ++i) {
        int idx = tid + i * 256;
        if (idx < NSTG) {
            int col  = idx % SC;
            int rest = idx / SC;
            int row  = rest % SR, cg = rest / SR;
            int gh = h0 + row - 1, gw = w0 + col - 1;
            bool ok = ((unsigned)gh < (unsigned)Hh) && ((unsigned)gw < (unsigned)Ww);
            const float* src = xn + (size_t)(cg * 8) * HW + gh * Ww + gw;
            float v[8];
#pragma unroll
            for (int j = 0; j < 8; ++j)
                v[j] = ok ? src[(size_t)j * HW] : 0.f;
            int widx = (row * SC + col) * 64 + ((cg ^ (col & 7)) << 3);
            *(int4*)&xs[widx] = make_int4(pkh(v[0], v[1]), pkh(v[2], v[3]),
                                          pkh(v[4], v[5]), pkh(v[6], v[7]));
        }
    }
    __syncthreads();   // the ONLY barrier

    // ---- MFMA conv: address arrays scoped HERE so they die before softmax ----
    const int g8 = (lane >> 4) << 3;
    f32x4 acc0, acc1;
    {
        int cbase[3], chg[3][2];
#pragma unroll
        for (int dj = 0; dj < 3; ++dj) {
            int swz = (((lane & 15) + dj) & 7) << 3;
            chg[dj][0] = g8 ^ swz;
            chg[dj][1] = (32 | g8) ^ swz;
            cbase[dj]  = (q * SC + (lane & 15) + dj) * 64;
        }

        f32x4 z = {0.f, 0.f, 0.f, 0.f};
        acc0 = z; acc1 = z;
#pragma unroll
        for (int kb = 0; kb < NKB; ++kb) {
            const int p = kb >> 1, di = p / 3, dj = p % 3, ch = kb & 1;
            const int a0 = cbase[dj] + di * (SC * 64) + chg[dj][ch];
            f16x8 b0 = *(const f16x8*)&xs[a0];
            f16x8 b1 = *(const f16x8*)&xs[a0 + 16 * 64];
            acc0 = __builtin_amdgcn_mfma_f32_16x16x32_f16(af[kb], b0, acc0, 0, 0, 0);
            acc1 = __builtin_amdgcn_mfma_f32_16x16x32_f16(af[kb], b1, acc1, 0, 0, 0);
        }
    }

    // ---- softmax (shfl), filter -> fb; +1.0 folded into tap 4 ----
    const float g0 = gamma[0];
    const int gidx = lane >> 4;
    const int k0 = gidx * 4;
    const float NEG = -3.0e38f;
    const float b4 = (gidx == 1) ? 1.f : 0.f;   // k0==4 -> e0 slot is tap 4

    f32x4 accs[2] = {acc0, acc1};
#pragma unroll
    for (int mt = 0; mt < 2; ++mt) {
        float a0 = accs[mt][0], a1 = accs[mt][1], a2 = accs[mt][2], a3 = accs[mt][3];
        float m0 = (gidx < 3) ? a0 : NEG;
        float m1 = (gidx < 2) ? a1 : NEG;
        float m2 = (gidx < 2) ? a2 : NEG;
        float m3 = (gidx < 2) ? a3 : NEG;
        float m = fmaxf(fmaxf(m0, m1), fmaxf(m2, m3));
        m = fmaxf(m, __shfl_xor(m, 16));
        m = fmaxf(m, __shfl_xor(m, 32));
        float e0 = (gidx < 3) ? __expf(a0 - m) : 0.f;
        float e1 = (gidx < 2) ? __expf(a1 - m) : 0.f;
        float e2 = (gidx < 2) ? __expf(a2 - m) : 0.f;
        float e3 = (gidx < 2) ? __expf(a3 - m) : 0.f;
        float s = (e0 + e1) + (e2 + e3);
        s += __shfl_xor(s, 16);
        s += __shfl_xor(s, 32);
        const float gs = g0 / s;
        const int px = q * 32 + mt * 16 + (lane & 15);
        if (gidx < 2) {
            *(unsigned*)&fb[px * FBS + k0]     = pkh(e0 * gs + b4, e1 * gs);
            *(unsigned*)&fb[px * FBS + k0 + 2] = pkh(e2 * gs, e3 * gs);
        } else if (gidx == 2) {
            fb[px * FBS + 8] = f2h(e0 * gs);
        }
    }
    // NO barrier: wave q reads back only row-q filters (lgkmcnt orders DS ops)

    // ---- pass 2: combine, conflict-free addressing, ALL addresses inline ----
    // lane owns pixels pxA = (lane&15) and pxB = pxA+16 of row q.
    const int l15 = lane & 15;
    float fA[9], fB[9];
    {
        const int pxA = q * 32 + l15;
        union { int4 i; f16x8 h; } ca; ca.i = *(const int4*)&fb[pxA * FBS];
        union { int4 i; f16x8 h; } cb; cb.i = *(const int4*)&fb[(pxA + 16) * FBS];
#pragma unroll
        for (int k = 0; k < 8; ++k) { fA[k] = (float)ca.h[k]; fB[k] = (float)cb.h[k]; }
        fA[8] = h2f((unsigned short)fb[pxA * FBS + 8]);
        fB[8] = h2f((unsigned short)fb[(pxA + 16) * FBS + 8]);
    }

    float* outp = out + (size_t)n * Cc * HW + (size_t)(h0 + q) * Ww + (w0 + l15);

#pragma unroll
    for (int hh = 0; hh < 2; ++hh) {
        float aA[8], aB[8];
#pragma unroll
        for (int j = 0; j < 8; ++j) { aA[j] = 0.f; aB[j] = 0.f; }
#pragma unroll
        for (int p = 0; p < 9; ++p) {
            const int di = p / 3, dj = p % 3;           // compile-time consts
            const int col  = l15 + dj;
            const int addr = ((q + di) * SC + col) * 64
                           + ((((hh << 5) | g8) ^ ((col & 7) << 3)));
            union { int4 i; f16x8 h; } c0; c0.i = *(const int4*)&xs[addr];
            union { int4 i; f16x8 h; } c1; c1.i = *(const int4*)&xs[addr + 16 * 64];
#pragma unroll
            for (int j = 0; j < 8; ++j) {
                aA[j] = fmaf(fA[p], (float)c0.h[j], aA[j]);
                aB[j] = fmaf(fB[p], (float)c1.h[j], aB[j]);
            }
        }
        const int c0ch = hh * 32 + g8;
#pragma unroll
        for (int j = 0; j < 8; ++j) {
            outp[(size_t)(c0ch + j) * HW]      = aA[j];
            outp[(size_t)(c0ch + j) * HW + 16] = aB[j];
        }
    }
}

extern "C" void kernel_launch(void* const* d_in, const int* in_sizes, int n_in,
                              void* d_out, int out_size, void* d_ws, size_t ws_size,
                              hipStream_t stream) {
    const float* x  = (const float*)d_in[0];
    const float* cw = (const float*)d_in[1];
    const float* gm = (const float*)d_in[2];
    float* out = (float*)d_out;
    unsigned short* blob = (unsigned short*)d_ws;   // 9216 f16 = 18 KB

    k_wprep<<<dim3((BLOB_N + 255) / 256), dim3(256), 0, stream>>>(cw, blob);
    k_main <<<dim3(NWG), dim3(256), 0, stream>>>(x, blob, gm, out);
}